// Round 1
// baseline (101.865 us; speedup 1.0000x reference)
//
#include <hip/hip_runtime.h>
#include <math.h>

#define PPB 256    // pixels (rays) per block
#define CHUNK 512  // points per LDS chunk

// ---------------------------------------------------------------------------
// Kernel A: per-batch prep.
//  - pack points as (qx,qy,qz, 0.5*|q|^2) float4 for the main loop
//  - max_distance[b] = max_n ||cam_loc - pc[b,n]||
// ---------------------------------------------------------------------------
__global__ __launch_bounds__(256) void prep_kernel(
    const float* __restrict__ c, const float* __restrict__ pc,
    float4* __restrict__ pts4, float* __restrict__ maxdist, int N)
{
    int b = blockIdx.x;
    const float* cb = c + b * 25;
    float ox = cb[3], oy = cb[7], oz = cb[11];   // cam2world[:3,3]
    const float* p = pc + (size_t)b * N * 3;
    float mx = -3.4e38f;
    for (int n = threadIdx.x; n < N; n += blockDim.x) {
        float qx = p[n * 3 + 0], qy = p[n * 3 + 1], qz = p[n * 3 + 2];
        float qn = qx * qx + qy * qy + qz * qz;
        pts4[(size_t)b * N + n] = make_float4(qx, qy, qz, 0.5f * qn);
        float dx = qx - ox, dy = qy - oy, dz = qz - oz;
        mx = fmaxf(mx, dx * dx + dy * dy + dz * dz);
    }
    for (int off = 32; off; off >>= 1) mx = fmaxf(mx, __shfl_down(mx, off));
    __shared__ float sred[8];
    int wid = threadIdx.x >> 6;
    if ((threadIdx.x & 63) == 0) sred[wid] = mx;
    __syncthreads();
    if (threadIdx.x == 0) {
        float m2 = sred[0];
        int nw = blockDim.x >> 6;
        for (int w = 1; w < nw; ++w) m2 = fmaxf(m2, sred[w]);
        maxdist[b] = sqrtf(m2);
    }
}

// ---------------------------------------------------------------------------
// Kernel B: main chamfer min.  grid = (M/PPB, ceil(N/CHUNK), B)
// Each thread owns one ray; min over its point chunk; merged with atomicMin
// on a monotonic-uint encoding of the fp32 min distance.
// ---------------------------------------------------------------------------
__global__ __launch_bounds__(256) void chamfer_kernel(
    const float* __restrict__ c, const float* __restrict__ depth,
    const float4* __restrict__ pts4, unsigned int* __restrict__ minbuf,
    int res, int M, int N)
{
    int b = blockIdx.z;
    int m = blockIdx.x * PPB + (int)threadIdx.x;
    int n0 = blockIdx.y * CHUNK;
    int nend = min(N - n0, CHUNK);

    __shared__ float4 spts[CHUNK];
    {
        const float4* src = pts4 + (size_t)b * N + n0;
        for (int k = threadIdx.x; k < nend; k += blockDim.x) spts[k] = src[k];
    }
    __syncthreads();
    if (m >= M) return;

    // --- ray for pixel m ---
    const float* cb = c + b * 25;
    float fx = cb[16], sk = cb[17], cx = cb[18];
    float fy = cb[20], cy = cb[21];
    int i = m / res, j = m - i * res;
    float x = (j + 0.5f) / (float)res;
    float y = (i + 0.5f) / (float)res;
    float xl = (x - cx + cy * sk / fy - sk * y / fy) / fx;
    float yl = (y - cy) / fy;
    // world = cam2world * [xl, yl, 1, 1]
    float wx = cb[0] * xl + cb[1] * yl + cb[2] + cb[3];
    float wy = cb[4] * xl + cb[5] * yl + cb[6] + cb[7];
    float wz = cb[8] * xl + cb[9] * yl + cb[10] + cb[11];
    float ox = cb[3], oy = cb[7], oz = cb[11];
    float dx = wx - ox, dy = wy - oy, dz = wz - oz;
    float nrm = fmaxf(sqrtf(dx * dx + dy * dy + dz * dz), 1e-12f);
    dx = dx / nrm; dy = dy / nrm; dz = dz / nrm;
    float d = depth[(size_t)b * M + m];
    float px = fmaf(d, dx, ox), py = fmaf(d, dy, oy), pz = fmaf(d, dz, oz);
    float pn = px * px + py * py + pz * pz;

    // min_n d2 = pn - 2 * max_n (p.q - 0.5*|q|^2)
    float maxs = -3.4e38f;
    #pragma unroll 8
    for (int k = 0; k < nend; ++k) {
        float4 q = spts[k];
        float s = fmaf(px, q.x, -q.w);
        s = fmaf(py, q.y, s);
        s = fmaf(pz, q.z, s);
        maxs = fmaxf(maxs, s);
    }
    float md = fmaf(-2.0f, maxs, pn);

    unsigned int bb = __float_as_uint(md);
    unsigned int u = (bb >> 31) ? ~bb : (bb | 0x80000000u);
    atomicMin(&minbuf[(size_t)b * M + m], u);
}

// ---------------------------------------------------------------------------
// Kernel C: per-batch masked mean.  grid = B
// ---------------------------------------------------------------------------
__global__ __launch_bounds__(256) void reduce_kernel(
    const unsigned int* __restrict__ minbuf, const float* __restrict__ depth,
    const float* __restrict__ maxdist, float* __restrict__ out, int M)
{
    int b = blockIdx.x;
    float thr = maxdist[b];
    float sum = 0.f, cnt = 0.f;
    for (int m = threadIdx.x; m < M; m += blockDim.x) {
        unsigned int u = minbuf[(size_t)b * M + m];
        unsigned int bb = (u >> 31) ? (u ^ 0x80000000u) : ~u;
        float md = fmaxf(__uint_as_float(bb), 0.0f);
        float dpt = depth[(size_t)b * M + m];
        if (dpt < thr) { sum += md; cnt += 1.0f; }
    }
    for (int off = 32; off; off >>= 1) {
        sum += __shfl_down(sum, off);
        cnt += __shfl_down(cnt, off);
    }
    __shared__ float ss[8], sc[8];
    int wid = threadIdx.x >> 6;
    if ((threadIdx.x & 63) == 0) { ss[wid] = sum; sc[wid] = cnt; }
    __syncthreads();
    if (threadIdx.x == 0) {
        float S = 0.f, C = 0.f;
        int nw = blockDim.x >> 6;
        for (int w = 0; w < nw; ++w) { S += ss[w]; C += sc[w]; }
        out[b] = S / fmaxf(C, 1.0f);
    }
}

extern "C" void kernel_launch(void* const* d_in, const int* in_sizes, int n_in,
                              void* d_out, int out_size, void* d_ws, size_t ws_size,
                              hipStream_t stream) {
    const float* c     = (const float*)d_in[0];
    const float* depth = (const float*)d_in[1];
    const float* pc    = (const float*)d_in[2];

    int B = in_sizes[0] / 25;
    int M = in_sizes[1] / B;
    int N = in_sizes[2] / (3 * B);
    int res = 1;
    while (res * res < M) ++res;

    float4* pts4 = (float4*)d_ws;
    char* base = (char*)d_ws;
    size_t off_maxdist = (size_t)B * N * sizeof(float4);
    float* maxdist = (float*)(base + off_maxdist);
    unsigned int* minbuf = (unsigned int*)(base + off_maxdist + 256);

    hipMemsetAsync(minbuf, 0xFF, (size_t)B * M * sizeof(unsigned int), stream);
    prep_kernel<<<B, 256, 0, stream>>>(c, pc, pts4, maxdist, N);

    int chunks = (N + CHUNK - 1) / CHUNK;
    dim3 grid((M + PPB - 1) / PPB, chunks, B);
    chamfer_kernel<<<grid, 256, 0, stream>>>(c, depth, pts4, minbuf, res, M, N);

    reduce_kernel<<<B, 256, 0, stream>>>(minbuf, depth, maxdist, (float*)d_out, M);
}

// Round 2
// 25.913 us; speedup vs baseline: 3.9310x; 3.9310x over previous
//
#include <hip/hip_runtime.h>
#include <math.h>

#define WAVES 8
#define TPB 512          // 8 waves
#define RPT 4            // rays per thread
#define RAYS_PB 256      // 64 lanes * RPT
#define MAXPTS 2048      // points staged in LDS per pass (32 KB)

// ---------------------------------------------------------------------------
// Kernel A: per-batch prep.
//  - pack points as (qx,qy,qz, -0.5*|q|^2) float4
//  - max_distance[b] = max_n ||cam_loc - pc[b,n]||
// ---------------------------------------------------------------------------
__global__ __launch_bounds__(256) void prep_kernel(
    const float* __restrict__ c, const float* __restrict__ pc,
    float4* __restrict__ pts4, float* __restrict__ maxdist, int N)
{
    int b = blockIdx.x;
    const float* cb = c + b * 25;
    float ox = cb[3], oy = cb[7], oz = cb[11];   // cam2world[:3,3]
    const float* p = pc + (size_t)b * N * 3;
    float mx = -3.4e38f;
    for (int n = threadIdx.x; n < N; n += blockDim.x) {
        float qx = p[n * 3 + 0], qy = p[n * 3 + 1], qz = p[n * 3 + 2];
        float qn = qx * qx + qy * qy + qz * qz;
        pts4[(size_t)b * N + n] = make_float4(qx, qy, qz, -0.5f * qn);
        float dx = qx - ox, dy = qy - oy, dz = qz - oz;
        mx = fmaxf(mx, dx * dx + dy * dy + dz * dz);
    }
    for (int off = 32; off; off >>= 1) mx = fmaxf(mx, __shfl_down(mx, off));
    __shared__ float sred[8];
    int wid = threadIdx.x >> 6;
    if ((threadIdx.x & 63) == 0) sred[wid] = mx;
    __syncthreads();
    if (threadIdx.x == 0) {
        float m2 = sred[0];
        int nw = blockDim.x >> 6;
        for (int w = 1; w < nw; ++w) m2 = fmaxf(m2, sred[w]);
        maxdist[b] = sqrtf(m2);
    }
}

// ---------------------------------------------------------------------------
// Kernel B: main chamfer.  grid = (M/RAYS_PB, 1, B), block = 512 (8 waves).
// Block covers 256 rays; all N points staged in LDS; wave w scans its own
// N/8 chunk for all 256 rays (4 rays/thread); cross-wave max-combine in LDS;
// masked sum/count written as deterministic per-block partials.
// min_n d2 = pn + 2 * (-max_n (p.q - 0.5|q|^2))  with q.w = -0.5|q|^2
// ---------------------------------------------------------------------------
__global__ __launch_bounds__(TPB) void chamfer_kernel(
    const float* __restrict__ c, const float* __restrict__ depth,
    const float4* __restrict__ pts4, const float* __restrict__ maxdist,
    float2* __restrict__ partial, int res, int M, int N)
{
    __shared__ float4 spts[MAXPTS];
    __shared__ float red[WAVES][RAYS_PB];
    __shared__ float bs[WAVES], bc[WAVES];

    int b = blockIdx.z;
    int r0 = blockIdx.x * RAYS_PB;
    int tid = threadIdx.x;
    int w = tid >> 6, lane = tid & 63;

    const float* cb = c + b * 25;
    float fx = cb[16], sk = cb[17], cx = cb[18];
    float fy = cb[20], cy = cb[21];
    float ox = cb[3], oy = cb[7], oz = cb[11];

    float px[RPT], py[RPT], pz[RPT], pn[RPT], dep[RPT], mxs[RPT];
    #pragma unroll
    for (int r = 0; r < RPT; ++r) {
        int m = r0 + lane + 64 * r;
        int mm = min(m, M - 1);
        int i = mm / res, j = mm - i * res;
        float x = (j + 0.5f) / (float)res;
        float y = (i + 0.5f) / (float)res;
        float xl = (x - cx + cy * sk / fy - sk * y / fy) / fx;
        float yl = (y - cy) / fy;
        float wx = cb[0] * xl + cb[1] * yl + cb[2] + cb[3];
        float wy = cb[4] * xl + cb[5] * yl + cb[6] + cb[7];
        float wz = cb[8] * xl + cb[9] * yl + cb[10] + cb[11];
        float dx = wx - ox, dy = wy - oy, dz = wz - oz;
        float nrm = fmaxf(sqrtf(dx * dx + dy * dy + dz * dz), 1e-12f);
        dx /= nrm; dy /= nrm; dz /= nrm;
        float d = depth[(size_t)b * M + mm];
        dep[r] = d;
        px[r] = fmaf(d, dx, ox);
        py[r] = fmaf(d, dy, oy);
        pz[r] = fmaf(d, dz, oz);
        pn[r] = px[r] * px[r] + py[r] * py[r] + pz[r] * pz[r];
        mxs[r] = -3.4e38f;
    }

    for (int n0 = 0; n0 < N; n0 += MAXPTS) {
        int nend = min(N - n0, MAXPTS);
        __syncthreads();
        const float4* src = pts4 + (size_t)b * N + n0;
        for (int k2 = tid; k2 < nend; k2 += TPB) spts[k2] = src[k2];
        __syncthreads();
        int cpw = (nend + WAVES - 1) / WAVES;
        int ks = min(w * cpw, nend);
        int kc = min(nend - ks, cpw);
        const float4* sp = spts + ks;
        #pragma unroll 8
        for (int k = 0; k < kc; ++k) {
            float4 q = sp[k];
            #pragma unroll
            for (int r = 0; r < RPT; ++r) {
                float s = fmaf(px[r], q.x, q.w);
                s = fmaf(py[r], q.y, s);
                s = fmaf(pz[r], q.z, s);
                mxs[r] = fmaxf(mxs[r], s);
            }
        }
    }

    #pragma unroll
    for (int r = 0; r < RPT; ++r) red[w][lane + 64 * r] = mxs[r];
    __syncthreads();

    float s = 0.f, cnt = 0.f;
    if (tid < RAYS_PB) {
        float mx = red[0][tid];
        #pragma unroll
        for (int ww = 1; ww < WAVES; ++ww) mx = fmaxf(mx, red[ww][tid]);
        int k = tid >> 6;
        // static-index select (avoid runtime-indexed register array -> scratch)
        float pnk = pn[0], dk = dep[0];
        #pragma unroll
        for (int r = 1; r < RPT; ++r) if (k == r) { pnk = pn[r]; dk = dep[r]; }
        int m = r0 + tid;
        if (m < M) {
            float md = fmaxf(fmaf(2.0f, mx, pnk), 0.0f);  // pn + 2*max(-(p.q-h)) ... q.w folded sign
            // note: mxs accumulated s = p.q - 0.5|q|^2, so min d2 = pn - 2*mx
            md = fmaxf(fmaf(-2.0f, mx, pnk), 0.0f);
            if (dk < maxdist[b]) { s = md; cnt = 1.0f; }
        }
    }
    for (int off = 32; off; off >>= 1) {
        s += __shfl_down(s, off);
        cnt += __shfl_down(cnt, off);
    }
    if (lane == 0) { bs[w] = s; bc[w] = cnt; }
    __syncthreads();
    if (tid == 0) {
        float S = 0.f, C = 0.f;
        #pragma unroll
        for (int ww = 0; ww < WAVES; ++ww) { S += bs[ww]; C += bc[ww]; }
        partial[(size_t)b * gridDim.x + blockIdx.x] = make_float2(S, C);
    }
}

// ---------------------------------------------------------------------------
// Kernel C: finalize.  grid = B, block = 64 (one wave).
// ---------------------------------------------------------------------------
__global__ __launch_bounds__(64) void finalize_kernel(
    const float2* __restrict__ partial, float* __restrict__ out, int nblk)
{
    int b = blockIdx.x;
    float S = 0.f, C = 0.f;
    for (int i = threadIdx.x; i < nblk; i += 64) {
        float2 p = partial[(size_t)b * nblk + i];
        S += p.x; C += p.y;
    }
    for (int off = 32; off; off >>= 1) {
        S += __shfl_down(S, off);
        C += __shfl_down(C, off);
    }
    if (threadIdx.x == 0) out[b] = S / fmaxf(C, 1.0f);
}

extern "C" void kernel_launch(void* const* d_in, const int* in_sizes, int n_in,
                              void* d_out, int out_size, void* d_ws, size_t ws_size,
                              hipStream_t stream) {
    const float* c     = (const float*)d_in[0];
    const float* depth = (const float*)d_in[1];
    const float* pc    = (const float*)d_in[2];

    int B = in_sizes[0] / 25;
    int M = in_sizes[1] / B;
    int N = in_sizes[2] / (3 * B);
    int res = 1;
    while (res * res < M) ++res;

    char* base = (char*)d_ws;
    float4* pts4 = (float4*)base;
    size_t off_maxdist = (size_t)B * N * sizeof(float4);
    float* maxdist = (float*)(base + off_maxdist);
    float2* partial = (float2*)(base + off_maxdist + 256);

    int nblk = (M + RAYS_PB - 1) / RAYS_PB;

    prep_kernel<<<B, 256, 0, stream>>>(c, pc, pts4, maxdist, N);

    dim3 grid(nblk, 1, B);
    chamfer_kernel<<<grid, TPB, 0, stream>>>(c, depth, pts4, maxdist, partial,
                                             res, M, N);

    finalize_kernel<<<B, 64, 0, stream>>>(partial, (float*)d_out, nblk);
}